// Round 1
// baseline (589.678 us; speedup 1.0000x reference)
//
#include <hip/hip_runtime.h>
#include <math.h>

#define N_NODES 50000
#define N_EDGES 800000
#define EP (N_EDGES + N_NODES)   /* 850000 edges incl self-loops */
#define DIN 256
#define HEADS 4
#define HID 64
#define F1 256   /* HEADS*HID */
#define F2 128
#define NEG_SLOPE 0.2f

static __device__ __forceinline__ float leaky(float x){ return x > 0.f ? x : NEG_SLOPE*x; }
static __device__ __forceinline__ float elu_f(float x){ return x > 0.f ? x : (__expf(x)-1.f); }

// ---------------- CSR build ----------------
__global__ __launch_bounds__(256) void k_hist(const int* __restrict__ dst, int* __restrict__ counts){
  int e = blockIdx.x*256 + threadIdx.x;
  if (e >= EP) return;
  int d = (e < N_EDGES) ? dst[e] : (e - N_EDGES);
  atomicAdd(&counts[d], 1);
}

__global__ __launch_bounds__(1024) void k_scan(const int* __restrict__ counts, int* __restrict__ offsets){
  __shared__ int sums[1024];
  int t = threadIdx.x;
  const int CH = (N_NODES + 1023)/1024; // 49
  int base = t*CH;
  int s = 0;
  for (int i=0;i<CH;i++){ int idx=base+i; if (idx<N_NODES) s += counts[idx]; }
  sums[t]=s; __syncthreads();
  for (int off=1; off<1024; off<<=1){
    int v = (t>=off)? sums[t-off]:0;
    __syncthreads();
    sums[t]+=v;
    __syncthreads();
  }
  int excl = (t==0)?0:sums[t-1];
  for (int i=0;i<CH;i++){ int idx=base+i; if (idx<N_NODES){ offsets[idx]=excl; excl += counts[idx]; } }
  if (t==1023) offsets[N_NODES]=excl;
}

__global__ __launch_bounds__(256) void k_scatter(const int* __restrict__ src, const int* __restrict__ dst,
                          int* __restrict__ cursor, int* __restrict__ sorted_src){
  int e = blockIdx.x*256 + threadIdx.x;
  if (e >= EP) return;
  int s, d;
  if (e < N_EDGES){ s = src[e]; d = dst[e]; } else { s = d = e - N_EDGES; }
  int pos = atomicAdd(&cursor[d], 1);
  sorted_src[pos] = s;
}

// ---------------- f32 tiled GEMM: C[M,Nc] = A[M,K] @ B[K,Nc] ----------------
template<int BM, int BN, int BK>
__global__ __launch_bounds__(256) void k_gemm(const float* __restrict__ A, const float* __restrict__ B,
                       float* __restrict__ C, int M, int Nc, int K){
  __shared__ float As[BK][BM+4];
  __shared__ float Bs[BK][BN+4];
  int tid = threadIdx.x;
  int row0 = blockIdx.x*BM;
  int col0 = blockIdx.y*BN;
  int tr = (tid/16)*4, tc = (tid%16)*4;
  int am = tid/4;          // 0..63
  int ak = (tid%4)*4;      // 0,4,8,12
  int bkr = tid/16;        // 0..15
  int bn = (tid%16)*4;
  float acc[4][4] = {};
  for (int k0=0; k0<K; k0+=BK){
    float4 av = {0.f,0.f,0.f,0.f};
    int gr = row0+am;
    if (gr < M) av = *(const float4*)(A + (size_t)gr*K + k0 + ak);
    As[ak+0][am]=av.x; As[ak+1][am]=av.y; As[ak+2][am]=av.z; As[ak+3][am]=av.w;
    float4 bv = *(const float4*)(B + (size_t)(k0+bkr)*Nc + col0 + bn);
    *(float4*)&Bs[bkr][bn] = bv;
    __syncthreads();
    #pragma unroll
    for (int kk=0; kk<BK; kk++){
      float4 a4 = *(const float4*)&As[kk][tr];
      float4 b4 = *(const float4*)&Bs[kk][tc];
      float aa[4] = {a4.x,a4.y,a4.z,a4.w};
      float bb[4] = {b4.x,b4.y,b4.z,b4.w};
      #pragma unroll
      for (int i=0;i<4;i++)
        #pragma unroll
        for (int j=0;j<4;j++)
          acc[i][j] = fmaf(aa[i], bb[j], acc[i][j]);
    }
    __syncthreads();
  }
  #pragma unroll
  for (int i=0;i<4;i++){
    int gr = row0+tr+i;
    if (gr < M) *(float4*)(C + (size_t)gr*Nc + col0 + tc) = *(float4*)&acc[i][0];
  }
}

// ---------------- attention dot products ----------------
__global__ __launch_bounds__(256) void k_edot1(const float* __restrict__ h1, const float* __restrict__ a_src,
                        const float* __restrict__ a_dst, float* __restrict__ es, float* __restrict__ ed){
  int wave = threadIdx.x>>6, lane = threadIdx.x&63;
  int n = blockIdx.x*4 + wave;
  if (n >= N_NODES) return;
  float4 h = *(const float4*)(h1 + (size_t)n*F1 + lane*4);
  float4 s4 = *(const float4*)(a_src + lane*4);
  float4 d4 = *(const float4*)(a_dst + lane*4);
  float ps = h.x*s4.x + h.y*s4.y + h.z*s4.z + h.w*s4.w;
  float pd = h.x*d4.x + h.y*d4.y + h.z*d4.z + h.w*d4.w;
  #pragma unroll
  for (int m=1;m<16;m<<=1){ ps += __shfl_xor(ps,m); pd += __shfl_xor(pd,m); }
  if ((lane&15)==0){ es[n*HEADS + (lane>>4)] = ps; ed[n*HEADS + (lane>>4)] = pd; }
}

__global__ __launch_bounds__(256) void k_edot2(const float* __restrict__ h2, const float* __restrict__ a_src,
                        const float* __restrict__ a_dst, float* __restrict__ es, float* __restrict__ ed){
  int wave=threadIdx.x>>6, lane=threadIdx.x&63;
  int n = blockIdx.x*4+wave; if (n>=N_NODES) return;
  float2 h = *(const float2*)(h2 + (size_t)n*F2 + lane*2);
  float2 s2 = *(const float2*)(a_src + lane*2);
  float2 d2 = *(const float2*)(a_dst + lane*2);
  float ps = h.x*s2.x + h.y*s2.y;
  float pd = h.x*d2.x + h.y*d2.y;
  #pragma unroll
  for (int m=1;m<64;m<<=1){ ps += __shfl_xor(ps,m); pd += __shfl_xor(pd,m); }
  if (lane==0){ es[n]=ps; ed[n]=pd; }
}

// ---------------- layer-1 aggregation (4 heads x 64 ch), fused softmax ----------------
__global__ __launch_bounds__(256) void k_agg1(const float* __restrict__ h1, const float* __restrict__ es,
                       const float* __restrict__ ed, const int* __restrict__ offsets,
                       const int* __restrict__ ssrc, const float* __restrict__ b1,
                       float* __restrict__ out){
  int wave = threadIdx.x>>6, lane = threadIdx.x&63;
  int d = blockIdx.x*4 + wave;
  if (d >= N_NODES) return;
  int beg = offsets[d], end = offsets[d+1];
  float4 edv4 = *(const float4*)(ed + d*4);
  float edv[4] = {edv4.x, edv4.y, edv4.z, edv4.w};
  float m[4] = {-1e30f,-1e30f,-1e30f,-1e30f};
  float s[4] = {0.f,0.f,0.f,0.f};
  for (int i=beg+lane; i<end; i+=64){
    int sn = ssrc[i];
    float4 ev = *(const float4*)(es + sn*4);
    float lg[4] = { leaky(ev.x+edv[0]), leaky(ev.y+edv[1]), leaky(ev.z+edv[2]), leaky(ev.w+edv[3]) };
    #pragma unroll
    for (int h=0;h<4;h++){
      float M = fmaxf(m[h], lg[h]);
      s[h] = s[h]*__expf(m[h]-M) + __expf(lg[h]-M);
      m[h] = M;
    }
  }
  #pragma unroll
  for (int h=0;h<4;h++){
    #pragma unroll
    for (int off=1; off<64; off<<=1){
      float m2 = __shfl_xor(m[h], off);
      float s2 = __shfl_xor(s[h], off);
      float M = fmaxf(m[h], m2);
      s[h] = s[h]*__expf(m[h]-M) + s2*__expf(m2-M);
      m[h] = M;
    }
  }
  int head = lane>>4;
  float mh = m[head];
  float invh = 1.f/(s[head]+1e-16f);
  float edh = edv[head];
  float4 acc = {0.f,0.f,0.f,0.f};
  for (int i=beg; i<end; i++){
    int sn = ssrc[i];
    float lg = leaky(es[sn*4 + head] + edh);
    float alpha = __expf(lg - mh) * invh;
    float4 v = *(const float4*)(h1 + (size_t)sn*F1 + lane*4);
    acc.x = fmaf(alpha, v.x, acc.x);
    acc.y = fmaf(alpha, v.y, acc.y);
    acc.z = fmaf(alpha, v.z, acc.z);
    acc.w = fmaf(alpha, v.w, acc.w);
  }
  float4 bb = *(const float4*)(b1 + lane*4);
  float4 o;
  o.x = elu_f(acc.x + bb.x);
  o.y = elu_f(acc.y + bb.y);
  o.z = elu_f(acc.z + bb.z);
  o.w = elu_f(acc.w + bb.w);
  *(float4*)(out + (size_t)d*F1 + lane*4) = o;
}

// ---------------- layer-2 aggregation (1 head x 128 ch) + final mean ----------------
__global__ __launch_bounds__(256) void k_agg2(const float* __restrict__ h2, const float* __restrict__ es,
                       const float* __restrict__ ed, const int* __restrict__ offsets,
                       const int* __restrict__ ssrc, const float* __restrict__ b2,
                       float* __restrict__ out){
  int wave=threadIdx.x>>6, lane=threadIdx.x&63;
  int d = blockIdx.x*4+wave; if (d>=N_NODES) return;
  int beg=offsets[d], end=offsets[d+1];
  float edv = ed[d];
  float m=-1e30f, s=0.f;
  for (int i=beg+lane;i<end;i+=64){
    float lg = leaky(es[ssrc[i]] + edv);
    float M = fmaxf(m,lg); s = s*__expf(m-M)+__expf(lg-M); m=M;
  }
  #pragma unroll
  for (int off=1;off<64;off<<=1){
    float m2=__shfl_xor(m,off), ss=__shfl_xor(s,off);
    float M=fmaxf(m,m2); s = s*__expf(m-M)+ss*__expf(m2-M); m=M;
  }
  float inv = 1.f/(s+1e-16f);
  float2 acc={0.f,0.f};
  for (int i=beg;i<end;i++){
    int sn = ssrc[i];
    float alpha = __expf(leaky(es[sn]+edv)-m)*inv;
    float2 v = *(const float2*)(h2 + (size_t)sn*F2 + lane*2);
    acc.x = fmaf(alpha,v.x,acc.x);
    acc.y = fmaf(alpha,v.y,acc.y);
  }
  float2 bb = *(const float2*)(b2 + lane*2);
  float r = elu_f(acc.x+bb.x) + elu_f(acc.y+bb.y);
  #pragma unroll
  for (int off=1;off<64;off<<=1) r += __shfl_xor(r,off);
  if (lane==0) out[d] = r * (1.f/128.f);
}

extern "C" void kernel_launch(void* const* d_in, const int* in_sizes, int n_in,
                              void* d_out, int out_size, void* d_ws, size_t ws_size,
                              hipStream_t stream) {
  const float* x   = (const float*)d_in[0];
  const int*   ei  = (const int*)d_in[1];
  const int*   esrc = ei;
  const int*   edst = ei + N_EDGES;
  const float* W1  = (const float*)d_in[2];
  const float* a1s = (const float*)d_in[3];
  const float* a1d = (const float*)d_in[4];
  const float* b1  = (const float*)d_in[5];
  const float* W2  = (const float*)d_in[6];
  const float* a2s = (const float*)d_in[7];
  const float* a2d = (const float*)d_in[8];
  const float* b2  = (const float*)d_in[9];
  float* out = (float*)d_out;

  char* ws = (char*)d_ws;
  size_t off = 0;
  auto alloc = [&](size_t bytes)->void*{ void* p = ws + off; off += (bytes + 255) & ~(size_t)255; return p; };
  float* h1    = (float*)alloc((size_t)N_NODES*F1*4);
  float* hact  = (float*)alloc((size_t)N_NODES*F1*4);
  float* e1s   = (float*)alloc((size_t)N_NODES*HEADS*4);
  float* e1d   = (float*)alloc((size_t)N_NODES*HEADS*4);
  float* e2s   = (float*)alloc((size_t)N_NODES*4);
  float* e2d   = (float*)alloc((size_t)N_NODES*4);
  int*   counts= (int*)alloc((size_t)N_NODES*4);
  int*   offs  = (int*)alloc((size_t)(N_NODES+1)*4);
  int*   cursor= (int*)alloc((size_t)N_NODES*4);
  int*   ssrc  = (int*)alloc((size_t)EP*4);
  float* h2 = h1;  // h1 dead after k_agg1; reuse for layer-2 features

  hipMemsetAsync(counts, 0, (size_t)N_NODES*4, stream);
  k_hist<<<(EP+255)/256, 256, 0, stream>>>(edst, counts);
  k_scan<<<1, 1024, 0, stream>>>(counts, offs);
  hipMemcpyAsync(cursor, offs, (size_t)N_NODES*4, hipMemcpyDeviceToDevice, stream);
  k_scatter<<<(EP+255)/256, 256, 0, stream>>>(esrc, edst, cursor, ssrc);

  dim3 g1((N_NODES+63)/64, F1/64);
  k_gemm<64,64,16><<<g1, 256, 0, stream>>>(x, W1, h1, N_NODES, F1, DIN);
  k_edot1<<<(N_NODES+3)/4, 256, 0, stream>>>(h1, a1s, a1d, e1s, e1d);
  k_agg1<<<(N_NODES+3)/4, 256, 0, stream>>>(h1, e1s, e1d, offs, ssrc, b1, hact);

  dim3 g2((N_NODES+63)/64, F2/64);
  k_gemm<64,64,16><<<g2, 256, 0, stream>>>(hact, W2, h2, N_NODES, F2, F1);
  k_edot2<<<(N_NODES+3)/4, 256, 0, stream>>>(h2, a2s, a2d, e2s, e2d);
  k_agg2<<<(N_NODES+3)/4, 256, 0, stream>>>(h2, e2s, e2d, offs, ssrc, b2, out);
}

// Round 2
// 566.494 us; speedup vs baseline: 1.0409x; 1.0409x over previous
//
#include <hip/hip_runtime.h>
#include <math.h>

#define N_NODES 50000
#define N_EDGES 800000
#define EP (N_EDGES + N_NODES)
#define DIN 256
#define HEADS 4
#define HID 64
#define F1 256
#define F2 128
#define NEG_SLOPE 0.2f

static __device__ __forceinline__ float leaky(float x){ return x > 0.f ? x : NEG_SLOPE*x; }
static __device__ __forceinline__ float elu_f(float x){ return x > 0.f ? x : (__expf(x)-1.f); }

// ---------------- CSR build ----------------
__global__ __launch_bounds__(256) void k_hist(const int* __restrict__ dst, int* __restrict__ counts){
  int e = blockIdx.x*256 + threadIdx.x;
  if (e >= EP) return;
  int d = (e < N_EDGES) ? dst[e] : (e - N_EDGES);
  atomicAdd(&counts[d], 1);
}

__global__ __launch_bounds__(1024) void k_scan(const int* __restrict__ counts, int* __restrict__ offsets,
                                               int* __restrict__ cursor){
  __shared__ int sums[1024];
  int t = threadIdx.x;
  const int CH = (N_NODES + 1023)/1024;
  int base = t*CH;
  int s = 0;
  for (int i=0;i<CH;i++){ int idx=base+i; if (idx<N_NODES) s += counts[idx]; }
  sums[t]=s; __syncthreads();
  for (int off=1; off<1024; off<<=1){
    int v = (t>=off)? sums[t-off]:0;
    __syncthreads();
    sums[t]+=v;
    __syncthreads();
  }
  int excl = (t==0)?0:sums[t-1];
  for (int i=0;i<CH;i++){
    int idx=base+i;
    if (idx<N_NODES){ offsets[idx]=excl; cursor[idx]=excl; excl += counts[idx]; }
  }
  if (t==1023) offsets[N_NODES]=excl;
}

__global__ __launch_bounds__(256) void k_scatter(const int* __restrict__ src, const int* __restrict__ dst,
                          int* __restrict__ cursor, int* __restrict__ sorted_src){
  int e = blockIdx.x*256 + threadIdx.x;
  if (e >= EP) return;
  int s, d;
  if (e < N_EDGES){ s = src[e]; d = dst[e]; } else { s = d = e - N_EDGES; }
  int pos = atomicAdd(&cursor[d], 1);
  sorted_src[pos] = s;
}

// ---------------- f32 GEMM 128x128x16, 8x8 micro-tile ----------------
__global__ __launch_bounds__(256,4) void k_gemm128(const float* __restrict__ A, const float* __restrict__ B,
                       float* __restrict__ C, int M, int Nc, int K){
  constexpr int BM=128, BN=128, BK=16;
  __shared__ float As[BK][BM+4];
  __shared__ float Bs[BK][BN+4];
  int tid = threadIdx.x;
  int row0 = blockIdx.x*BM, col0 = blockIdx.y*BN;
  int tr = (tid/16)*8, tc = (tid%16)*8;
  int ar = tid/4;            // 0..63 (+64 second half)
  int ak = (tid%4)*4;
  int br = tid/32;           // 0..7 (+8 second half)
  int bc = (tid%32)*4;
  float acc[8][8] = {};
  for (int k0=0; k0<K; k0+=BK){
    int gr1 = row0+ar, gr2 = row0+ar+64;
    float4 av1 = {0,0,0,0}, av2 = {0,0,0,0};
    if (gr1 < M) av1 = *(const float4*)(A + (size_t)gr1*K + k0 + ak);
    if (gr2 < M) av2 = *(const float4*)(A + (size_t)gr2*K + k0 + ak);
    float4 bv1 = *(const float4*)(B + (size_t)(k0+br  )*Nc + col0 + bc);
    float4 bv2 = *(const float4*)(B + (size_t)(k0+br+8)*Nc + col0 + bc);
    As[ak+0][ar]=av1.x; As[ak+1][ar]=av1.y; As[ak+2][ar]=av1.z; As[ak+3][ar]=av1.w;
    As[ak+0][ar+64]=av2.x; As[ak+1][ar+64]=av2.y; As[ak+2][ar+64]=av2.z; As[ak+3][ar+64]=av2.w;
    *(float4*)&Bs[br  ][bc] = bv1;
    *(float4*)&Bs[br+8][bc] = bv2;
    __syncthreads();
    #pragma unroll
    for (int kk=0; kk<BK; kk++){
      float4 aA = *(const float4*)&As[kk][tr];
      float4 aB = *(const float4*)&As[kk][tr+4];
      float4 bA = *(const float4*)&Bs[kk][tc];
      float4 bB = *(const float4*)&Bs[kk][tc+4];
      float av[8] = {aA.x,aA.y,aA.z,aA.w,aB.x,aB.y,aB.z,aB.w};
      float bvv[8] = {bA.x,bA.y,bA.z,bA.w,bB.x,bB.y,bB.z,bB.w};
      #pragma unroll
      for (int i=0;i<8;i++)
        #pragma unroll
        for (int j=0;j<8;j++)
          acc[i][j] = fmaf(av[i], bvv[j], acc[i][j]);
    }
    __syncthreads();
  }
  #pragma unroll
  for (int i=0;i<8;i++){
    int gr = row0+tr+i;
    if (gr < M){
      float4 c0 = {acc[i][0],acc[i][1],acc[i][2],acc[i][3]};
      float4 c1 = {acc[i][4],acc[i][5],acc[i][6],acc[i][7]};
      *(float4*)(C + (size_t)gr*Nc + col0 + tc    ) = c0;
      *(float4*)(C + (size_t)gr*Nc + col0 + tc + 4) = c1;
    }
  }
}

// ---------------- attention dot products ----------------
__global__ __launch_bounds__(256) void k_edot1(const float* __restrict__ h1, const float* __restrict__ a_src,
                        const float* __restrict__ a_dst, float* __restrict__ es, float* __restrict__ ed){
  int wave = threadIdx.x>>6, lane = threadIdx.x&63;
  int n = blockIdx.x*4 + wave;
  if (n >= N_NODES) return;
  float4 h = *(const float4*)(h1 + (size_t)n*F1 + lane*4);
  float4 s4 = *(const float4*)(a_src + lane*4);
  float4 d4 = *(const float4*)(a_dst + lane*4);
  float ps = h.x*s4.x + h.y*s4.y + h.z*s4.z + h.w*s4.w;
  float pd = h.x*d4.x + h.y*d4.y + h.z*d4.z + h.w*d4.w;
  #pragma unroll
  for (int m=1;m<16;m<<=1){ ps += __shfl_xor(ps,m); pd += __shfl_xor(pd,m); }
  if ((lane&15)==0){ es[n*HEADS + (lane>>4)] = ps; ed[n*HEADS + (lane>>4)] = pd; }
}

__global__ __launch_bounds__(256) void k_edot2(const float* __restrict__ h2, const float* __restrict__ a_src,
                        const float* __restrict__ a_dst, float* __restrict__ es, float* __restrict__ ed){
  int wave=threadIdx.x>>6, lane=threadIdx.x&63;
  int n = blockIdx.x*4+wave; if (n>=N_NODES) return;
  float2 h = *(const float2*)(h2 + (size_t)n*F2 + lane*2);
  float2 s2 = *(const float2*)(a_src + lane*2);
  float2 d2 = *(const float2*)(a_dst + lane*2);
  float ps = h.x*s2.x + h.y*s2.y;
  float pd = h.x*d2.x + h.y*d2.y;
  #pragma unroll
  for (int m=1;m<64;m<<=1){ ps += __shfl_xor(ps,m); pd += __shfl_xor(pd,m); }
  if (lane==0){ es[n]=ps; ed[n]=pd; }
}

// online-softmax update helper
static __device__ __forceinline__ void osm(float& m, float& s, float lg){
  float M = fmaxf(m, lg);
  s = s*__expf(m-M) + __expf(lg-M);
  m = M;
}

// ---------------- layer-1 aggregation: alpha precomputed in LDS ----------------
__global__ __launch_bounds__(256) void k_agg1(const float* __restrict__ h1, const float* __restrict__ es,
                       const float* __restrict__ ed, const int* __restrict__ offsets,
                       const int* __restrict__ ssrc, const float* __restrict__ b1,
                       float* __restrict__ out){
  __shared__ float alds[4][64][4];   // per-wave normalized alphas, 4KB
  int wave = threadIdx.x>>6, lane = threadIdx.x&63;
  int d = blockIdx.x*4 + wave;
  if (d >= N_NODES) return;
  int beg = offsets[d], end = offsets[d+1];
  int deg = end - beg;
  float4 edv = *(const float4*)(ed + d*4);
  float m0=-1e30f,m1=-1e30f,m2=-1e30f,m3=-1e30f;
  float s0=0.f,s1=0.f,s2=0.f,s3=0.f;
  float4 mylg = {0,0,0,0};
  for (int j=lane; j<deg; j+=64){
    int sn = ssrc[beg+j];
    float4 ev = *(const float4*)(es + (size_t)sn*4);
    float4 lg;
    lg.x = leaky(ev.x+edv.x); lg.y = leaky(ev.y+edv.y);
    lg.z = leaky(ev.z+edv.z); lg.w = leaky(ev.w+edv.w);
    if (j == lane) mylg = lg;
    osm(m0,s0,lg.x); osm(m1,s1,lg.y); osm(m2,s2,lg.z); osm(m3,s3,lg.w);
  }
  #pragma unroll
  for (int off=1; off<64; off<<=1){
    float mm, ss, M;
    mm=__shfl_xor(m0,off); ss=__shfl_xor(s0,off); M=fmaxf(m0,mm); s0=s0*__expf(m0-M)+ss*__expf(mm-M); m0=M;
    mm=__shfl_xor(m1,off); ss=__shfl_xor(s1,off); M=fmaxf(m1,mm); s1=s1*__expf(m1-M)+ss*__expf(mm-M); m1=M;
    mm=__shfl_xor(m2,off); ss=__shfl_xor(s2,off); M=fmaxf(m2,mm); s2=s2*__expf(m2-M)+ss*__expf(mm-M); m2=M;
    mm=__shfl_xor(m3,off); ss=__shfl_xor(s3,off); M=fmaxf(m3,mm); s3=s3*__expf(m3-M)+ss*__expf(mm-M); m3=M;
  }
  float i0=1.f/(s0+1e-16f), i1=1.f/(s1+1e-16f), i2=1.f/(s2+1e-16f), i3=1.f/(s3+1e-16f);
  int n1 = deg < 64 ? deg : 64;
  if (lane < n1){
    alds[wave][lane][0] = __expf(mylg.x-m0)*i0;
    alds[wave][lane][1] = __expf(mylg.y-m1)*i1;
    alds[wave][lane][2] = __expf(mylg.z-m2)*i2;
    alds[wave][lane][3] = __expf(mylg.w-m3)*i3;
  }
  asm volatile("s_waitcnt lgkmcnt(0)" ::: "memory");
  int head = lane>>4;
  int ch = lane;  // float4 per lane covers 256 ch
  float4 acc0={0,0,0,0}, acc1={0,0,0,0}, acc2={0,0,0,0}, acc3={0,0,0,0};
  int j=0;
  for (; j+4<=n1; j+=4){
    int sn0=ssrc[beg+j], sn1=ssrc[beg+j+1], sn2=ssrc[beg+j+2], sn3=ssrc[beg+j+3];
    float a0=alds[wave][j+0][head], a1=alds[wave][j+1][head];
    float a2=alds[wave][j+2][head], a3=alds[wave][j+3][head];
    float4 v0 = *((const float4*)(h1 + (size_t)sn0*F1) + ch);
    float4 v1 = *((const float4*)(h1 + (size_t)sn1*F1) + ch);
    float4 v2 = *((const float4*)(h1 + (size_t)sn2*F1) + ch);
    float4 v3 = *((const float4*)(h1 + (size_t)sn3*F1) + ch);
    acc0.x=fmaf(a0,v0.x,acc0.x); acc0.y=fmaf(a0,v0.y,acc0.y); acc0.z=fmaf(a0,v0.z,acc0.z); acc0.w=fmaf(a0,v0.w,acc0.w);
    acc1.x=fmaf(a1,v1.x,acc1.x); acc1.y=fmaf(a1,v1.y,acc1.y); acc1.z=fmaf(a1,v1.z,acc1.z); acc1.w=fmaf(a1,v1.w,acc1.w);
    acc2.x=fmaf(a2,v2.x,acc2.x); acc2.y=fmaf(a2,v2.y,acc2.y); acc2.z=fmaf(a2,v2.z,acc2.z); acc2.w=fmaf(a2,v2.w,acc2.w);
    acc3.x=fmaf(a3,v3.x,acc3.x); acc3.y=fmaf(a3,v3.y,acc3.y); acc3.z=fmaf(a3,v3.z,acc3.z); acc3.w=fmaf(a3,v3.w,acc3.w);
  }
  for (; j<n1; j++){
    int sn=ssrc[beg+j];
    float a=alds[wave][j][head];
    float4 v = *((const float4*)(h1 + (size_t)sn*F1) + ch);
    acc0.x=fmaf(a,v.x,acc0.x); acc0.y=fmaf(a,v.y,acc0.y); acc0.z=fmaf(a,v.z,acc0.z); acc0.w=fmaf(a,v.w,acc0.w);
  }
  if (deg > 64){  // rare overflow path: recompute alpha
    float mh = head==0?m0:(head==1?m1:(head==2?m2:m3));
    float ih = head==0?i0:(head==1?i1:(head==2?i2:i3));
    float eh = head==0?edv.x:(head==1?edv.y:(head==2?edv.z:edv.w));
    for (j=64; j<deg; j++){
      int sn=ssrc[beg+j];
      float e = es[(size_t)sn*4+head];
      float a = __expf(leaky(e+eh)-mh)*ih;
      float4 v = *((const float4*)(h1 + (size_t)sn*F1) + ch);
      acc0.x=fmaf(a,v.x,acc0.x); acc0.y=fmaf(a,v.y,acc0.y); acc0.z=fmaf(a,v.z,acc0.z); acc0.w=fmaf(a,v.w,acc0.w);
    }
  }
  float4 acc;
  acc.x = acc0.x+acc1.x+acc2.x+acc3.x;
  acc.y = acc0.y+acc1.y+acc2.y+acc3.y;
  acc.z = acc0.z+acc1.z+acc2.z+acc3.z;
  acc.w = acc0.w+acc1.w+acc2.w+acc3.w;
  float4 bb = *(const float4*)(b1 + lane*4);
  float4 o;
  o.x = elu_f(acc.x + bb.x);
  o.y = elu_f(acc.y + bb.y);
  o.z = elu_f(acc.z + bb.z);
  o.w = elu_f(acc.w + bb.w);
  *(float4*)(out + (size_t)d*F1 + lane*4) = o;
}

// ---------------- layer-2 aggregation + final mean ----------------
__global__ __launch_bounds__(256) void k_agg2(const float* __restrict__ h2, const float* __restrict__ es,
                       const float* __restrict__ ed, const int* __restrict__ offsets,
                       const int* __restrict__ ssrc, const float* __restrict__ b2,
                       float* __restrict__ out){
  __shared__ float alds[4][64];
  int wave=threadIdx.x>>6, lane=threadIdx.x&63;
  int d = blockIdx.x*4+wave; if (d>=N_NODES) return;
  int beg=offsets[d], end=offsets[d+1];
  int deg=end-beg;
  float edv = ed[d];
  float m=-1e30f, s=0.f, mylg=0.f;
  for (int j=lane;j<deg;j+=64){
    float lg = leaky(es[ssrc[beg+j]] + edv);
    if (j==lane) mylg = lg;
    osm(m,s,lg);
  }
  #pragma unroll
  for (int off=1;off<64;off<<=1){
    float m2=__shfl_xor(m,off), ss=__shfl_xor(s,off);
    float M=fmaxf(m,m2); s = s*__expf(m-M)+ss*__expf(m2-M); m=M;
  }
  float inv = 1.f/(s+1e-16f);
  int n1 = deg < 64 ? deg : 64;
  if (lane < n1) alds[wave][lane] = __expf(mylg-m)*inv;
  asm volatile("s_waitcnt lgkmcnt(0)" ::: "memory");
  float2 acc0={0,0}, acc1={0,0}, acc2={0,0}, acc3={0,0};
  int j=0;
  for (; j+4<=n1; j+=4){
    int sn0=ssrc[beg+j], sn1=ssrc[beg+j+1], sn2=ssrc[beg+j+2], sn3=ssrc[beg+j+3];
    float a0=alds[wave][j], a1=alds[wave][j+1], a2=alds[wave][j+2], a3=alds[wave][j+3];
    float2 v0 = *((const float2*)(h2 + (size_t)sn0*F2) + lane);
    float2 v1 = *((const float2*)(h2 + (size_t)sn1*F2) + lane);
    float2 v2 = *((const float2*)(h2 + (size_t)sn2*F2) + lane);
    float2 v3 = *((const float2*)(h2 + (size_t)sn3*F2) + lane);
    acc0.x=fmaf(a0,v0.x,acc0.x); acc0.y=fmaf(a0,v0.y,acc0.y);
    acc1.x=fmaf(a1,v1.x,acc1.x); acc1.y=fmaf(a1,v1.y,acc1.y);
    acc2.x=fmaf(a2,v2.x,acc2.x); acc2.y=fmaf(a2,v2.y,acc2.y);
    acc3.x=fmaf(a3,v3.x,acc3.x); acc3.y=fmaf(a3,v3.y,acc3.y);
  }
  for (; j<n1; j++){
    int sn=ssrc[beg+j];
    float a=alds[wave][j];
    float2 v = *((const float2*)(h2 + (size_t)sn*F2) + lane);
    acc0.x=fmaf(a,v.x,acc0.x); acc0.y=fmaf(a,v.y,acc0.y);
  }
  if (deg > 64){
    for (j=64; j<deg; j++){
      int sn=ssrc[beg+j];
      float a = __expf(leaky(es[sn]+edv)-m)*inv;
      float2 v = *((const float2*)(h2 + (size_t)sn*F2) + lane);
      acc0.x=fmaf(a,v.x,acc0.x); acc0.y=fmaf(a,v.y,acc0.y);
    }
  }
  float2 acc;
  acc.x = acc0.x+acc1.x+acc2.x+acc3.x;
  acc.y = acc0.y+acc1.y+acc2.y+acc3.y;
  float2 bb = *(const float2*)(b2 + lane*2);
  float r = elu_f(acc.x+bb.x) + elu_f(acc.y+bb.y);
  #pragma unroll
  for (int off=1;off<64;off<<=1) r += __shfl_xor(r,off);
  if (lane==0) out[d] = r * (1.f/128.f);
}

extern "C" void kernel_launch(void* const* d_in, const int* in_sizes, int n_in,
                              void* d_out, int out_size, void* d_ws, size_t ws_size,
                              hipStream_t stream) {
  const float* x   = (const float*)d_in[0];
  const int*   ei  = (const int*)d_in[1];
  const int*   esrc = ei;
  const int*   edst = ei + N_EDGES;
  const float* W1  = (const float*)d_in[2];
  const float* a1s = (const float*)d_in[3];
  const float* a1d = (const float*)d_in[4];
  const float* b1  = (const float*)d_in[5];
  const float* W2  = (const float*)d_in[6];
  const float* a2s = (const float*)d_in[7];
  const float* a2d = (const float*)d_in[8];
  const float* b2  = (const float*)d_in[9];
  float* out = (float*)d_out;

  char* ws = (char*)d_ws;
  size_t off = 0;
  auto alloc = [&](size_t bytes)->void*{ void* p = ws + off; off += (bytes + 255) & ~(size_t)255; return p; };
  float* h1    = (float*)alloc((size_t)N_NODES*F1*4);
  float* hact  = (float*)alloc((size_t)N_NODES*F1*4);
  float* e1s   = (float*)alloc((size_t)N_NODES*HEADS*4);
  float* e1d   = (float*)alloc((size_t)N_NODES*HEADS*4);
  float* e2s   = (float*)alloc((size_t)N_NODES*4);
  float* e2d   = (float*)alloc((size_t)N_NODES*4);
  int*   counts= (int*)alloc((size_t)N_NODES*4);
  int*   offs  = (int*)alloc((size_t)(N_NODES+1)*4);
  int*   cursor= (int*)alloc((size_t)N_NODES*4);
  int*   ssrc  = (int*)alloc((size_t)EP*4);
  float* h2 = h1;  // h1 dead after k_agg1

  hipMemsetAsync(counts, 0, (size_t)N_NODES*4, stream);
  k_hist<<<(EP+255)/256, 256, 0, stream>>>(edst, counts);
  k_scan<<<1, 1024, 0, stream>>>(counts, offs, cursor);
  k_scatter<<<(EP+255)/256, 256, 0, stream>>>(esrc, edst, cursor, ssrc);

  dim3 g1((N_NODES+127)/128, F1/128);
  k_gemm128<<<g1, 256, 0, stream>>>(x, W1, h1, N_NODES, F1, DIN);
  k_edot1<<<(N_NODES+3)/4, 256, 0, stream>>>(h1, a1s, a1d, e1s, e1d);
  k_agg1<<<(N_NODES+3)/4, 256, 0, stream>>>(h1, e1s, e1d, offs, ssrc, b1, hact);

  dim3 g2((N_NODES+127)/128, F2/128);
  k_gemm128<<<g2, 256, 0, stream>>>(hact, W2, h2, N_NODES, F2, F1);
  k_edot2<<<(N_NODES+3)/4, 256, 0, stream>>>(h2, a2s, a2d, e2s, e2d);
  k_agg2<<<(N_NODES+3)/4, 256, 0, stream>>>(h2, e2s, e2d, offs, ssrc, b2, out);
}

// Round 3
// 471.430 us; speedup vs baseline: 1.2508x; 1.2017x over previous
//
#include <hip/hip_runtime.h>
#include <math.h>

#define N_NODES 50000
#define M_PAD   50048            /* 391*128 */
#define N_EDGES 800000
#define EP (N_EDGES + N_NODES)
#define DIN 256
#define HEADS 4
#define HID 64
#define F1 256
#define F2 128
#define NEG_SLOPE 0.2f

typedef short bf16x8 __attribute__((ext_vector_type(8)));
typedef float f32x4  __attribute__((ext_vector_type(4)));

static __device__ __forceinline__ float leaky(float x){ return x > 0.f ? x : NEG_SLOPE*x; }
static __device__ __forceinline__ float elu_f(float x){ return x > 0.f ? x : (__expf(x)-1.f); }
static __device__ __forceinline__ float b2f(unsigned short u){ return __uint_as_float(((unsigned)u)<<16); }
static __device__ __forceinline__ unsigned short f2b(float f){
  unsigned u = __float_as_uint(f);
  return (unsigned short)((u + 0x7fffu + ((u>>16)&1u)) >> 16);   // RNE
}

// ---------------- CSR build ----------------
__global__ __launch_bounds__(256) void k_hist(const int* __restrict__ dst, int* __restrict__ counts){
  int e = blockIdx.x*256 + threadIdx.x;
  if (e >= EP) return;
  int d = (e < N_EDGES) ? dst[e] : (e - N_EDGES);
  atomicAdd(&counts[d], 1);
}

__global__ __launch_bounds__(1024) void k_scan(const int* __restrict__ counts, int* __restrict__ offsets,
                                               int* __restrict__ cursor){
  __shared__ int sums[1024];
  int t = threadIdx.x;
  const int CH = (N_NODES + 1023)/1024;
  int base = t*CH;
  int s = 0;
  for (int i=0;i<CH;i++){ int idx=base+i; if (idx<N_NODES) s += counts[idx]; }
  sums[t]=s; __syncthreads();
  for (int off=1; off<1024; off<<=1){
    int v = (t>=off)? sums[t-off]:0;
    __syncthreads();
    sums[t]+=v;
    __syncthreads();
  }
  int excl = (t==0)?0:sums[t-1];
  for (int i=0;i<CH;i++){
    int idx=base+i;
    if (idx<N_NODES){ offsets[idx]=excl; cursor[idx]=excl; excl += counts[idx]; }
  }
  if (t==1023) offsets[N_NODES]=excl;
}

__global__ __launch_bounds__(256) void k_scatter(const int* __restrict__ src, const int* __restrict__ dst,
                          int* __restrict__ cursor, int* __restrict__ sorted_src){
  int e = blockIdx.x*256 + threadIdx.x;
  if (e >= EP) return;
  int s, d;
  if (e < N_EDGES){ s = src[e]; d = dst[e]; } else { s = d = e - N_EDGES; }
  int pos = atomicAdd(&cursor[d], 1);
  sorted_src[pos] = s;
}

// ---------------- split f32 -> bf16 hi/lo (padded rows zeroed) ----------------
__global__ __launch_bounds__(256) void k_splitA(const float* __restrict__ X,
                         unsigned short* __restrict__ Ahi, unsigned short* __restrict__ Alo){
  int gid = blockIdx.x*256 + threadIdx.x;       // one float4 per thread
  size_t base = (size_t)gid*4;                  // element index, K=256 rows
  int row = (int)(base >> 8);
  ushort4 hi, lo;
  if (row < N_NODES){
    float4 v = *(const float4*)(X + base);
    hi.x=f2b(v.x); hi.y=f2b(v.y); hi.z=f2b(v.z); hi.w=f2b(v.w);
    lo.x=f2b(v.x-b2f(hi.x)); lo.y=f2b(v.y-b2f(hi.y));
    lo.z=f2b(v.z-b2f(hi.z)); lo.w=f2b(v.w-b2f(hi.w));
  } else {
    hi = {0,0,0,0}; lo = {0,0,0,0};
  }
  *(ushort4*)(Ahi + base) = hi;
  *(ushort4*)(Alo + base) = lo;
}

// W [Kd][Nd] f32 -> Bt hi/lo [Nd][Kd] bf16 (transpose + split)
__global__ __launch_bounds__(256) void k_splitWT(const float* __restrict__ W,
                          unsigned short* __restrict__ Bhi, unsigned short* __restrict__ Blo,
                          int Kd, int Nd){
  int t = blockIdx.x*256 + threadIdx.x;
  if (t >= Kd*Nd) return;
  int n = t / Kd, k = t % Kd;
  float v = W[(size_t)k*Nd + n];
  unsigned short hi = f2b(v);
  unsigned short lo = f2b(v - b2f(hi));
  Bhi[(size_t)n*Kd + k] = hi;
  Blo[(size_t)n*Kd + k] = lo;
}

// ---------------- bf16x3 MFMA GEMM: C[M_PAD][Nc](bf16) = A[M_PAD][256] @ Bt[Nc][256]^T --------
__global__ __launch_bounds__(256) void k_gemm_bf3(
    const unsigned short* __restrict__ Ahi, const unsigned short* __restrict__ Alo,
    const unsigned short* __restrict__ Bthi, const unsigned short* __restrict__ Btlo,
    unsigned short* __restrict__ Cbf, int Nc){
  const int K = 256;
  int tid = threadIdx.x;
  int wave = tid>>6, lane = tid&63;
  int wr = wave>>1, wc = wave&1;
  int row0 = blockIdx.x*128 + wr*64;
  int col0 = blockIdx.y*128 + wc*64;
  int lrow = lane&15, lk = (lane>>4)*8;
  f32x4 acc[4][4] = {};
  for (int ks=0; ks<K; ks+=32){
    bf16x8 ah[4], al[4], bh[4], bl[4];
    #pragma unroll
    for (int i=0;i<4;i++){
      size_t aoff = (size_t)(row0 + i*16 + lrow)*K + ks + lk;
      ah[i] = *(const bf16x8*)(Ahi + aoff);
      al[i] = *(const bf16x8*)(Alo + aoff);
      size_t boff = (size_t)(col0 + i*16 + lrow)*K + ks + lk;
      bh[i] = *(const bf16x8*)(Bthi + boff);
      bl[i] = *(const bf16x8*)(Btlo + boff);
    }
    #pragma unroll
    for (int i=0;i<4;i++)
      #pragma unroll
      for (int j=0;j<4;j++)
        acc[i][j] = __builtin_amdgcn_mfma_f32_16x16x32_bf16(ah[i], bh[j], acc[i][j], 0,0,0);
    #pragma unroll
    for (int i=0;i<4;i++)
      #pragma unroll
      for (int j=0;j<4;j++)
        acc[i][j] = __builtin_amdgcn_mfma_f32_16x16x32_bf16(ah[i], bl[j], acc[i][j], 0,0,0);
    #pragma unroll
    for (int i=0;i<4;i++)
      #pragma unroll
      for (int j=0;j<4;j++)
        acc[i][j] = __builtin_amdgcn_mfma_f32_16x16x32_bf16(al[i], bh[j], acc[i][j], 0,0,0);
  }
  int crow = (lane>>4)*4, ccol = lane&15;
  #pragma unroll
  for (int i=0;i<4;i++)
    #pragma unroll
    for (int j=0;j<4;j++)
      #pragma unroll
      for (int q=0;q<4;q++){
        int r = row0 + i*16 + crow + q;
        int c = col0 + j*16 + ccol;
        Cbf[(size_t)r*Nc + c] = f2b(acc[i][j][q]);
      }
}

// ---------------- attention dot products (bf16 features) ----------------
__global__ __launch_bounds__(256) void k_edot1(const unsigned short* __restrict__ h1bf, const float* __restrict__ a_src,
                        const float* __restrict__ a_dst, float* __restrict__ es, float* __restrict__ ed){
  int wave = threadIdx.x>>6, lane = threadIdx.x&63;
  int n = blockIdx.x*4 + wave;
  if (n >= N_NODES) return;
  ushort4 hv = ((const ushort4*)(h1bf + (size_t)n*F1))[lane];
  float4 s4 = ((const float4*)a_src)[lane];
  float4 d4 = ((const float4*)a_dst)[lane];
  float h0=b2f(hv.x), h1=b2f(hv.y), h2=b2f(hv.z), h3=b2f(hv.w);
  float ps = h0*s4.x + h1*s4.y + h2*s4.z + h3*s4.w;
  float pd = h0*d4.x + h1*d4.y + h2*d4.z + h3*d4.w;
  #pragma unroll
  for (int m=1;m<16;m<<=1){ ps += __shfl_xor(ps,m); pd += __shfl_xor(pd,m); }
  if ((lane&15)==0){ es[n*HEADS + (lane>>4)] = ps; ed[n*HEADS + (lane>>4)] = pd; }
}

__global__ __launch_bounds__(256) void k_edot2(const unsigned short* __restrict__ h2bf, const float* __restrict__ a_src,
                        const float* __restrict__ a_dst, float* __restrict__ es, float* __restrict__ ed){
  int wave=threadIdx.x>>6, lane=threadIdx.x&63;
  int n = blockIdx.x*4+wave; if (n>=N_NODES) return;
  ushort2 hv = ((const ushort2*)(h2bf + (size_t)n*F2))[lane];
  float2 s2 = ((const float2*)a_src)[lane];
  float2 d2 = ((const float2*)a_dst)[lane];
  float h0=b2f(hv.x), h1=b2f(hv.y);
  float ps = h0*s2.x + h1*s2.y;
  float pd = h0*d2.x + h1*d2.y;
  #pragma unroll
  for (int m=1;m<64;m<<=1){ ps += __shfl_xor(ps,m); pd += __shfl_xor(pd,m); }
  if (lane==0){ es[n]=ps; ed[n]=pd; }
}

static __device__ __forceinline__ void osm(float& m, float& s, float lg){
  float M = fmaxf(m, lg);
  s = s*__expf(m-M) + __expf(lg-M);
  m = M;
}

// ---------------- layer-1 aggregation: bf16 gather, writes layer-2 GEMM input hi/lo ----------
__global__ __launch_bounds__(256) void k_agg1(const unsigned short* __restrict__ h1bf, const float* __restrict__ es,
                       const float* __restrict__ ed, const int* __restrict__ offsets,
                       const int* __restrict__ ssrc, const float* __restrict__ b1,
                       unsigned short* __restrict__ A2hi, unsigned short* __restrict__ A2lo){
  __shared__ float alds[4][64][4];
  int wave = threadIdx.x>>6, lane = threadIdx.x&63;
  int d = blockIdx.x*4 + wave;
  if (d >= M_PAD) return;
  if (d >= N_NODES){                       // pad rows: zero for GEMM2
    ushort4 z = {0,0,0,0};
    ((ushort4*)(A2hi + (size_t)d*F1))[lane] = z;
    ((ushort4*)(A2lo + (size_t)d*F1))[lane] = z;
    return;
  }
  int beg = offsets[d], end = offsets[d+1];
  int deg = end - beg;
  float4 edv = *(const float4*)(ed + d*4);
  float m0=-1e30f,m1=-1e30f,m2=-1e30f,m3=-1e30f;
  float s0=0.f,s1=0.f,s2=0.f,s3=0.f;
  float4 mylg = {0,0,0,0};
  for (int j=lane; j<deg; j+=64){
    int sn = ssrc[beg+j];
    float4 ev = *(const float4*)(es + (size_t)sn*4);
    float4 lg;
    lg.x = leaky(ev.x+edv.x); lg.y = leaky(ev.y+edv.y);
    lg.z = leaky(ev.z+edv.z); lg.w = leaky(ev.w+edv.w);
    if (j == lane) mylg = lg;
    osm(m0,s0,lg.x); osm(m1,s1,lg.y); osm(m2,s2,lg.z); osm(m3,s3,lg.w);
  }
  #pragma unroll
  for (int off=1; off<64; off<<=1){
    float mm, ss, M;
    mm=__shfl_xor(m0,off); ss=__shfl_xor(s0,off); M=fmaxf(m0,mm); s0=s0*__expf(m0-M)+ss*__expf(mm-M); m0=M;
    mm=__shfl_xor(m1,off); ss=__shfl_xor(s1,off); M=fmaxf(m1,mm); s1=s1*__expf(m1-M)+ss*__expf(mm-M); m1=M;
    mm=__shfl_xor(m2,off); ss=__shfl_xor(s2,off); M=fmaxf(m2,mm); s2=s2*__expf(m2-M)+ss*__expf(mm-M); m2=M;
    mm=__shfl_xor(m3,off); ss=__shfl_xor(s3,off); M=fmaxf(m3,mm); s3=s3*__expf(m3-M)+ss*__expf(mm-M); m3=M;
  }
  float i0=1.f/(s0+1e-16f), i1=1.f/(s1+1e-16f), i2=1.f/(s2+1e-16f), i3=1.f/(s3+1e-16f);
  int n1 = deg < 64 ? deg : 64;
  if (lane < n1){
    alds[wave][lane][0] = __expf(mylg.x-m0)*i0;
    alds[wave][lane][1] = __expf(mylg.y-m1)*i1;
    alds[wave][lane][2] = __expf(mylg.z-m2)*i2;
    alds[wave][lane][3] = __expf(mylg.w-m3)*i3;
  }
  asm volatile("s_waitcnt lgkmcnt(0)" ::: "memory");
  int head = lane>>4;
  float4 acc0={0,0,0,0}, acc1={0,0,0,0}, acc2={0,0,0,0}, acc3={0,0,0,0};
  int j=0;
  for (; j+4<=n1; j+=4){
    int sn0=ssrc[beg+j], sn1=ssrc[beg+j+1], sn2=ssrc[beg+j+2], sn3=ssrc[beg+j+3];
    float a0=alds[wave][j+0][head], a1=alds[wave][j+1][head];
    float a2=alds[wave][j+2][head], a3=alds[wave][j+3][head];
    ushort4 v0 = ((const ushort4*)(h1bf + (size_t)sn0*F1))[lane];
    ushort4 v1 = ((const ushort4*)(h1bf + (size_t)sn1*F1))[lane];
    ushort4 v2 = ((const ushort4*)(h1bf + (size_t)sn2*F1))[lane];
    ushort4 v3 = ((const ushort4*)(h1bf + (size_t)sn3*F1))[lane];
    acc0.x=fmaf(a0,b2f(v0.x),acc0.x); acc0.y=fmaf(a0,b2f(v0.y),acc0.y); acc0.z=fmaf(a0,b2f(v0.z),acc0.z); acc0.w=fmaf(a0,b2f(v0.w),acc0.w);
    acc1.x=fmaf(a1,b2f(v1.x),acc1.x); acc1.y=fmaf(a1,b2f(v1.y),acc1.y); acc1.z=fmaf(a1,b2f(v1.z),acc1.z); acc1.w=fmaf(a1,b2f(v1.w),acc1.w);
    acc2.x=fmaf(a2,b2f(v2.x),acc2.x); acc2.y=fmaf(a2,b2f(v2.y),acc2.y); acc2.z=fmaf(a2,b2f(v2.z),acc2.z); acc2.w=fmaf(a2,b2f(v2.w),acc2.w);
    acc3.x=fmaf(a3,b2f(v3.x),acc3.x); acc3.y=fmaf(a3,b2f(v3.y),acc3.y); acc3.z=fmaf(a3,b2f(v3.z),acc3.z); acc3.w=fmaf(a3,b2f(v3.w),acc3.w);
  }
  for (; j<n1; j++){
    int sn=ssrc[beg+j];
    float a=alds[wave][j][head];
    ushort4 v = ((const ushort4*)(h1bf + (size_t)sn*F1))[lane];
    acc0.x=fmaf(a,b2f(v.x),acc0.x); acc0.y=fmaf(a,b2f(v.y),acc0.y); acc0.z=fmaf(a,b2f(v.z),acc0.z); acc0.w=fmaf(a,b2f(v.w),acc0.w);
  }
  if (deg > 64){
    float mh = head==0?m0:(head==1?m1:(head==2?m2:m3));
    float ih = head==0?i0:(head==1?i1:(head==2?i2:i3));
    float eh = head==0?edv.x:(head==1?edv.y:(head==2?edv.z:edv.w));
    for (j=64; j<deg; j++){
      int sn=ssrc[beg+j];
      float e = es[(size_t)sn*4+head];
      float a = __expf(leaky(e+eh)-mh)*ih;
      ushort4 v = ((const ushort4*)(h1bf + (size_t)sn*F1))[lane];
      acc0.x=fmaf(a,b2f(v.x),acc0.x); acc0.y=fmaf(a,b2f(v.y),acc0.y); acc0.z=fmaf(a,b2f(v.z),acc0.z); acc0.w=fmaf(a,b2f(v.w),acc0.w);
    }
  }
  float4 acc;
  acc.x = acc0.x+acc1.x+acc2.x+acc3.x;
  acc.y = acc0.y+acc1.y+acc2.y+acc3.y;
  acc.z = acc0.z+acc1.z+acc2.z+acc3.z;
  acc.w = acc0.w+acc1.w+acc2.w+acc3.w;
  float4 bb = *(const float4*)(b1 + lane*4);
  float4 o;
  o.x = elu_f(acc.x + bb.x);
  o.y = elu_f(acc.y + bb.y);
  o.z = elu_f(acc.z + bb.z);
  o.w = elu_f(acc.w + bb.w);
  ushort4 hi, lo;
  hi.x=f2b(o.x); lo.x=f2b(o.x-b2f(hi.x));
  hi.y=f2b(o.y); lo.y=f2b(o.y-b2f(hi.y));
  hi.z=f2b(o.z); lo.z=f2b(o.z-b2f(hi.z));
  hi.w=f2b(o.w); lo.w=f2b(o.w-b2f(hi.w));
  ((ushort4*)(A2hi + (size_t)d*F1))[lane] = hi;
  ((ushort4*)(A2lo + (size_t)d*F1))[lane] = lo;
}

// ---------------- layer-2 aggregation + final mean (bf16 gather) ----------------
__global__ __launch_bounds__(256) void k_agg2(const unsigned short* __restrict__ h2bf, const float* __restrict__ es,
                       const float* __restrict__ ed, const int* __restrict__ offsets,
                       const int* __restrict__ ssrc, const float* __restrict__ b2,
                       float* __restrict__ out){
  __shared__ float alds[4][64];
  int wave=threadIdx.x>>6, lane=threadIdx.x&63;
  int d = blockIdx.x*4+wave; if (d>=N_NODES) return;
  int beg=offsets[d], end=offsets[d+1];
  int deg=end-beg;
  float edv = ed[d];
  float m=-1e30f, s=0.f, mylg=0.f;
  for (int j=lane;j<deg;j+=64){
    float lg = leaky(es[ssrc[beg+j]] + edv);
    if (j==lane) mylg = lg;
    osm(m,s,lg);
  }
  #pragma unroll
  for (int off=1;off<64;off<<=1){
    float m2=__shfl_xor(m,off), ss=__shfl_xor(s,off);
    float M=fmaxf(m,m2); s = s*__expf(m-M)+ss*__expf(m2-M); m=M;
  }
  float inv = 1.f/(s+1e-16f);
  int n1 = deg < 64 ? deg : 64;
  if (lane < n1) alds[wave][lane] = __expf(mylg-m)*inv;
  asm volatile("s_waitcnt lgkmcnt(0)" ::: "memory");
  float2 acc0={0,0}, acc1={0,0}, acc2={0,0}, acc3={0,0};
  int j=0;
  for (; j+4<=n1; j+=4){
    int sn0=ssrc[beg+j], sn1=ssrc[beg+j+1], sn2=ssrc[beg+j+2], sn3=ssrc[beg+j+3];
    float a0=alds[wave][j], a1=alds[wave][j+1], a2=alds[wave][j+2], a3=alds[wave][j+3];
    ushort2 v0 = ((const ushort2*)(h2bf + (size_t)sn0*F2))[lane];
    ushort2 v1 = ((const ushort2*)(h2bf + (size_t)sn1*F2))[lane];
    ushort2 v2 = ((const ushort2*)(h2bf + (size_t)sn2*F2))[lane];
    ushort2 v3 = ((const ushort2*)(h2bf + (size_t)sn3*F2))[lane];
    acc0.x=fmaf(a0,b2f(v0.x),acc0.x); acc0.y=fmaf(a0,b2f(v0.y),acc0.y);
    acc1.x=fmaf(a1,b2f(v1.x),acc1.x); acc1.y=fmaf(a1,b2f(v1.y),acc1.y);
    acc2.x=fmaf(a2,b2f(v2.x),acc2.x); acc2.y=fmaf(a2,b2f(v2.y),acc2.y);
    acc3.x=fmaf(a3,b2f(v3.x),acc3.x); acc3.y=fmaf(a3,b2f(v3.y),acc3.y);
  }
  for (; j<n1; j++){
    int sn=ssrc[beg+j];
    float a=alds[wave][j];
    ushort2 v = ((const ushort2*)(h2bf + (size_t)sn*F2))[lane];
    acc0.x=fmaf(a,b2f(v.x),acc0.x); acc0.y=fmaf(a,b2f(v.y),acc0.y);
  }
  if (deg > 64){
    for (j=64; j<deg; j++){
      int sn=ssrc[beg+j];
      float a = __expf(leaky(es[sn]+edv)-m)*inv;
      ushort2 v = ((const ushort2*)(h2bf + (size_t)sn*F2))[lane];
      acc0.x=fmaf(a,b2f(v.x),acc0.x); acc0.y=fmaf(a,b2f(v.y),acc0.y);
    }
  }
  float2 acc;
  acc.x = acc0.x+acc1.x+acc2.x+acc3.x;
  acc.y = acc0.y+acc1.y+acc2.y+acc3.y;
  float2 bb = *(const float2*)(b2 + lane*2);
  float r = elu_f(acc.x+bb.x) + elu_f(acc.y+bb.y);
  #pragma unroll
  for (int off=1;off<64;off<<=1) r += __shfl_xor(r,off);
  if (lane==0) out[d] = r * (1.f/128.f);
}

extern "C" void kernel_launch(void* const* d_in, const int* in_sizes, int n_in,
                              void* d_out, int out_size, void* d_ws, size_t ws_size,
                              hipStream_t stream) {
  const float* x   = (const float*)d_in[0];
  const int*   ei  = (const int*)d_in[1];
  const int*   esrc = ei;
  const int*   edst = ei + N_EDGES;
  const float* W1  = (const float*)d_in[2];
  const float* a1s = (const float*)d_in[3];
  const float* a1d = (const float*)d_in[4];
  const float* b1  = (const float*)d_in[5];
  const float* W2  = (const float*)d_in[6];
  const float* a2s = (const float*)d_in[7];
  const float* a2d = (const float*)d_in[8];
  const float* b2  = (const float*)d_in[9];
  float* out = (float*)d_out;

  char* ws = (char*)d_ws;
  size_t off = 0;
  auto alloc = [&](size_t bytes)->void*{ void* p = ws + off; off += (bytes + 255) & ~(size_t)255; return p; };
  unsigned short* A1hi = (unsigned short*)alloc((size_t)M_PAD*F1*2);
  unsigned short* A1lo = (unsigned short*)alloc((size_t)M_PAD*F1*2);
  unsigned short* h1bf = (unsigned short*)alloc((size_t)M_PAD*F1*2);
  unsigned short* h2bf = (unsigned short*)alloc((size_t)M_PAD*F2*2);
  unsigned short* Bt1hi= (unsigned short*)alloc((size_t)F1*DIN*2);
  unsigned short* Bt1lo= (unsigned short*)alloc((size_t)F1*DIN*2);
  unsigned short* Bt2hi= (unsigned short*)alloc((size_t)F2*F1*2);
  unsigned short* Bt2lo= (unsigned short*)alloc((size_t)F2*F1*2);
  float* e1s   = (float*)alloc((size_t)N_NODES*HEADS*4);
  float* e1d   = (float*)alloc((size_t)N_NODES*HEADS*4);
  float* e2s   = (float*)alloc((size_t)N_NODES*4);
  float* e2d   = (float*)alloc((size_t)N_NODES*4);
  int*   counts= (int*)alloc((size_t)N_NODES*4);
  int*   offs  = (int*)alloc((size_t)(N_NODES+1)*4);
  int*   cursor= (int*)alloc((size_t)N_NODES*4);
  int*   ssrc  = (int*)alloc((size_t)EP*4);
  unsigned short* A2hi = A1hi;   // layer-1 inputs dead after gemm1
  unsigned short* A2lo = A1lo;

  hipMemsetAsync(counts, 0, (size_t)N_NODES*4, stream);
  k_hist<<<(EP+255)/256, 256, 0, stream>>>(edst, counts);
  k_scan<<<1, 1024, 0, stream>>>(counts, offs, cursor);
  k_scatter<<<(EP+255)/256, 256, 0, stream>>>(esrc, edst, cursor, ssrc);

  k_splitA<<<(M_PAD*F1/4 + 255)/256, 256, 0, stream>>>(x, A1hi, A1lo);
  k_splitWT<<<(DIN*F1 + 255)/256, 256, 0, stream>>>(W1, Bt1hi, Bt1lo, DIN, F1);
  k_splitWT<<<(F1*F2 + 255)/256, 256, 0, stream>>>(W2, Bt2hi, Bt2lo, F1, F2);

  dim3 g1(M_PAD/128, F1/128);
  k_gemm_bf3<<<g1, 256, 0, stream>>>(A1hi, A1lo, Bt1hi, Bt1lo, h1bf, F1);
  k_edot1<<<(N_NODES+3)/4, 256, 0, stream>>>(h1bf, a1s, a1d, e1s, e1d);
  k_agg1<<<(M_PAD+3)/4, 256, 0, stream>>>(h1bf, e1s, e1d, offs, ssrc, b1, A2hi, A2lo);

  dim3 g2(M_PAD/128, F2/128);
  k_gemm_bf3<<<g2, 256, 0, stream>>>(A2hi, A2lo, Bt2hi, Bt2lo, h2bf, F2);
  k_edot2<<<(N_NODES+3)/4, 256, 0, stream>>>(h2bf, a2s, a2d, e2s, e2d);
  k_agg2<<<(N_NODES+3)/4, 256, 0, stream>>>(h2bf, e2s, e2d, offs, ssrc, b2, out);
}

// Round 4
// 355.346 us; speedup vs baseline: 1.6594x; 1.3267x over previous
//
#include <hip/hip_runtime.h>
#include <math.h>

#define N_NODES 50000
#define M_PAD   50048            /* 391*128 */
#define N_EDGES 800000
#define EP (N_EDGES + N_NODES)
#define DIN 256
#define HEADS 4
#define HID 64
#define F1 256
#define F2 128
#define NEG_SLOPE 0.2f
#define SCAN_NBLK ((N_NODES + 255)/256)   /* 196 */

typedef short bf16x8 __attribute__((ext_vector_type(8)));
typedef float f32x4  __attribute__((ext_vector_type(4)));

static __device__ __forceinline__ float leaky(float x){ return x > 0.f ? x : NEG_SLOPE*x; }
static __device__ __forceinline__ float elu_f(float x){ return x > 0.f ? x : (__expf(x)-1.f); }
static __device__ __forceinline__ float b2f(unsigned short u){ return __uint_as_float(((unsigned)u)<<16); }
static __device__ __forceinline__ unsigned short f2b(float f){
  unsigned u = __float_as_uint(f);
  return (unsigned short)((u + 0x7fffu + ((u>>16)&1u)) >> 16);   // RNE
}

// ---------------- CSR build ----------------
__global__ __launch_bounds__(256) void k_hist(const int* __restrict__ dst, int* __restrict__ counts){
  int e = blockIdx.x*256 + threadIdx.x;
  if (e >= EP) return;
  int d = (e < N_EDGES) ? dst[e] : (e - N_EDGES);
  atomicAdd(&counts[d], 1);
}

// two-level scan: per-block exclusive prefix + block sums
__global__ __launch_bounds__(256) void k_scan1(const int* __restrict__ counts,
                                               int* __restrict__ exc, int* __restrict__ bsum){
  int i = blockIdx.x*256 + threadIdx.x;
  int v = (i < N_NODES) ? counts[i] : 0;
  int lane = threadIdx.x & 63, wave = threadIdx.x >> 6;
  int inc = v;
  #pragma unroll
  for (int off=1; off<64; off<<=1){
    int n = __shfl_up(inc, off);
    if (lane >= off) inc += n;
  }
  __shared__ int wsum[4];
  if (lane == 63) wsum[wave] = inc;
  __syncthreads();
  int wpre = 0;
  #pragma unroll
  for (int w=0; w<4; w++) if (w < wave) wpre += wsum[w];
  if (i < N_NODES) exc[i] = wpre + inc - v;
  if (threadIdx.x == 255) bsum[blockIdx.x] = wpre + inc;
}

__global__ __launch_bounds__(256) void k_scan2(const int* __restrict__ bsum,
                                               int* __restrict__ bpref, int* __restrict__ offsets){
  int i = threadIdx.x;
  int v = (i < SCAN_NBLK) ? bsum[i] : 0;
  int lane = threadIdx.x & 63, wave = threadIdx.x >> 6;
  int inc = v;
  #pragma unroll
  for (int off=1; off<64; off<<=1){
    int n = __shfl_up(inc, off);
    if (lane >= off) inc += n;
  }
  __shared__ int wsum[4];
  if (lane == 63) wsum[wave] = inc;
  __syncthreads();
  int wpre = 0;
  #pragma unroll
  for (int w=0; w<4; w++) if (w < wave) wpre += wsum[w];
  if (i < SCAN_NBLK) bpref[i] = wpre + inc - v;
  if (i == 255) offsets[N_NODES] = wpre + inc;   // grand total == EP
}

__global__ __launch_bounds__(256) void k_scan3(const int* __restrict__ exc, const int* __restrict__ bpref,
                                               int* __restrict__ offsets, int* __restrict__ cursor){
  int i = blockIdx.x*256 + threadIdx.x;
  if (i >= N_NODES) return;
  int o = exc[i] + bpref[blockIdx.x];
  offsets[i] = o;
  cursor[i] = o;
}

__global__ __launch_bounds__(256) void k_scatter(const int* __restrict__ src, const int* __restrict__ dst,
                          int* __restrict__ cursor, int* __restrict__ sorted_src){
  int e = blockIdx.x*256 + threadIdx.x;
  if (e >= EP) return;
  int s, d;
  if (e < N_EDGES){ s = src[e]; d = dst[e]; } else { s = d = e - N_EDGES; }
  int pos = atomicAdd(&cursor[d], 1);
  sorted_src[pos] = s;
}

// ---------------- split f32 -> bf16 hi/lo (padded rows zeroed) ----------------
__global__ __launch_bounds__(256) void k_splitA(const float* __restrict__ X,
                         unsigned short* __restrict__ Ahi, unsigned short* __restrict__ Alo){
  int gid = blockIdx.x*256 + threadIdx.x;
  size_t base = (size_t)gid*4;
  int row = (int)(base >> 8);
  ushort4 hi, lo;
  if (row < N_NODES){
    float4 v = *(const float4*)(X + base);
    hi.x=f2b(v.x); hi.y=f2b(v.y); hi.z=f2b(v.z); hi.w=f2b(v.w);
    lo.x=f2b(v.x-b2f(hi.x)); lo.y=f2b(v.y-b2f(hi.y));
    lo.z=f2b(v.z-b2f(hi.z)); lo.w=f2b(v.w-b2f(hi.w));
  } else {
    hi = {0,0,0,0}; lo = {0,0,0,0};
  }
  *(ushort4*)(Ahi + base) = hi;
  *(ushort4*)(Alo + base) = lo;
}

// W [Kd][Nd] f32 -> Bt hi/lo [Nd][Kd] bf16 (transpose + split)
__global__ __launch_bounds__(256) void k_splitWT(const float* __restrict__ W,
                          unsigned short* __restrict__ Bhi, unsigned short* __restrict__ Blo,
                          int Kd, int Nd){
  int t = blockIdx.x*256 + threadIdx.x;
  if (t >= Kd*Nd) return;
  int n = t / Kd, k = t % Kd;
  float v = W[(size_t)k*Nd + n];
  unsigned short hi = f2b(v);
  unsigned short lo = f2b(v - b2f(hi));
  Bhi[(size_t)n*Kd + k] = hi;
  Blo[(size_t)n*Kd + k] = lo;
}

// ---------------- bf16x3 MFMA GEMM: C[M_PAD][Nc](bf16) = A[M_PAD][256] @ Bt[Nc][256]^T --------
__global__ __launch_bounds__(256) void k_gemm_bf3(
    const unsigned short* __restrict__ Ahi, const unsigned short* __restrict__ Alo,
    const unsigned short* __restrict__ Bthi, const unsigned short* __restrict__ Btlo,
    unsigned short* __restrict__ Cbf, int Nc){
  const int K = 256;
  int tid = threadIdx.x;
  int wave = tid>>6, lane = tid&63;
  int wr = wave>>1, wc = wave&1;
  int row0 = blockIdx.x*128 + wr*64;
  int col0 = blockIdx.y*128 + wc*64;
  int lrow = lane&15, lk = (lane>>4)*8;
  f32x4 acc[4][4] = {};
  for (int ks=0; ks<K; ks+=32){
    bf16x8 ah[4], al[4], bh[4], bl[4];
    #pragma unroll
    for (int i=0;i<4;i++){
      size_t aoff = (size_t)(row0 + i*16 + lrow)*K + ks + lk;
      ah[i] = *(const bf16x8*)(Ahi + aoff);
      al[i] = *(const bf16x8*)(Alo + aoff);
      size_t boff = (size_t)(col0 + i*16 + lrow)*K + ks + lk;
      bh[i] = *(const bf16x8*)(Bthi + boff);
      bl[i] = *(const bf16x8*)(Btlo + boff);
    }
    #pragma unroll
    for (int i=0;i<4;i++)
      #pragma unroll
      for (int j=0;j<4;j++)
        acc[i][j] = __builtin_amdgcn_mfma_f32_16x16x32_bf16(ah[i], bh[j], acc[i][j], 0,0,0);
    #pragma unroll
    for (int i=0;i<4;i++)
      #pragma unroll
      for (int j=0;j<4;j++)
        acc[i][j] = __builtin_amdgcn_mfma_f32_16x16x32_bf16(ah[i], bl[j], acc[i][j], 0,0,0);
    #pragma unroll
    for (int i=0;i<4;i++)
      #pragma unroll
      for (int j=0;j<4;j++)
        acc[i][j] = __builtin_amdgcn_mfma_f32_16x16x32_bf16(al[i], bh[j], acc[i][j], 0,0,0);
  }
  int crow = (lane>>4)*4, ccol = lane&15;
  #pragma unroll
  for (int i=0;i<4;i++)
    #pragma unroll
    for (int j=0;j<4;j++)
      #pragma unroll
      for (int q=0;q<4;q++){
        int r = row0 + i*16 + crow + q;
        int c = col0 + j*16 + ccol;
        Cbf[(size_t)r*Nc + c] = f2b(acc[i][j][q]);
      }
}

// ---------------- attention dot products (bf16 features) ----------------
__global__ __launch_bounds__(256) void k_edot1(const unsigned short* __restrict__ h1bf, const float* __restrict__ a_src,
                        const float* __restrict__ a_dst, float* __restrict__ es, float* __restrict__ ed){
  int wave = threadIdx.x>>6, lane = threadIdx.x&63;
  int n = blockIdx.x*4 + wave;
  if (n >= N_NODES) return;
  ushort4 hv = ((const ushort4*)(h1bf + (size_t)n*F1))[lane];
  float4 s4 = ((const float4*)a_src)[lane];
  float4 d4 = ((const float4*)a_dst)[lane];
  float h0=b2f(hv.x), h1=b2f(hv.y), h2=b2f(hv.z), h3=b2f(hv.w);
  float ps = h0*s4.x + h1*s4.y + h2*s4.z + h3*s4.w;
  float pd = h0*d4.x + h1*d4.y + h2*d4.z + h3*d4.w;
  #pragma unroll
  for (int m=1;m<16;m<<=1){ ps += __shfl_xor(ps,m); pd += __shfl_xor(pd,m); }
  if ((lane&15)==0){ es[n*HEADS + (lane>>4)] = ps; ed[n*HEADS + (lane>>4)] = pd; }
}

__global__ __launch_bounds__(256) void k_edot2(const unsigned short* __restrict__ h2bf, const float* __restrict__ a_src,
                        const float* __restrict__ a_dst, float* __restrict__ es, float* __restrict__ ed){
  int wave=threadIdx.x>>6, lane=threadIdx.x&63;
  int n = blockIdx.x*4+wave; if (n>=N_NODES) return;
  ushort2 hv = ((const ushort2*)(h2bf + (size_t)n*F2))[lane];
  float2 s2 = ((const float2*)a_src)[lane];
  float2 d2 = ((const float2*)a_dst)[lane];
  float h0=b2f(hv.x), h1=b2f(hv.y);
  float ps = h0*s2.x + h1*s2.y;
  float pd = h0*d2.x + h1*d2.y;
  #pragma unroll
  for (int m=1;m<64;m<<=1){ ps += __shfl_xor(ps,m); pd += __shfl_xor(pd,m); }
  if (lane==0){ es[n]=ps; ed[n]=pd; }
}

static __device__ __forceinline__ void osm(float& m, float& s, float lg){
  float M = fmaxf(m, lg);
  s = s*__expf(m-M) + __expf(lg-M);
  m = M;
}

// ---------------- layer-1 aggregation: bf16 gather, writes layer-2 GEMM input hi/lo ----------
__global__ __launch_bounds__(256) void k_agg1(const unsigned short* __restrict__ h1bf, const float* __restrict__ es,
                       const float* __restrict__ ed, const int* __restrict__ offsets,
                       const int* __restrict__ ssrc, const float* __restrict__ b1,
                       unsigned short* __restrict__ A2hi, unsigned short* __restrict__ A2lo){
  __shared__ float alds[4][64][4];
  int wave = threadIdx.x>>6, lane = threadIdx.x&63;
  int d = blockIdx.x*4 + wave;
  if (d >= M_PAD) return;
  if (d >= N_NODES){
    ushort4 z = {0,0,0,0};
    ((ushort4*)(A2hi + (size_t)d*F1))[lane] = z;
    ((ushort4*)(A2lo + (size_t)d*F1))[lane] = z;
    return;
  }
  int beg = offsets[d], end = offsets[d+1];
  int deg = end - beg;
  float4 edv = *(const float4*)(ed + d*4);
  float m0=-1e30f,m1=-1e30f,m2=-1e30f,m3=-1e30f;
  float s0=0.f,s1=0.f,s2=0.f,s3=0.f;
  float4 mylg = {0,0,0,0};
  for (int j=lane; j<deg; j+=64){
    int sn = ssrc[beg+j];
    float4 ev = *(const float4*)(es + (size_t)sn*4);
    float4 lg;
    lg.x = leaky(ev.x+edv.x); lg.y = leaky(ev.y+edv.y);
    lg.z = leaky(ev.z+edv.z); lg.w = leaky(ev.w+edv.w);
    if (j == lane) mylg = lg;
    osm(m0,s0,lg.x); osm(m1,s1,lg.y); osm(m2,s2,lg.z); osm(m3,s3,lg.w);
  }
  #pragma unroll
  for (int off=1; off<64; off<<=1){
    float mm, ss, M;
    mm=__shfl_xor(m0,off); ss=__shfl_xor(s0,off); M=fmaxf(m0,mm); s0=s0*__expf(m0-M)+ss*__expf(mm-M); m0=M;
    mm=__shfl_xor(m1,off); ss=__shfl_xor(s1,off); M=fmaxf(m1,mm); s1=s1*__expf(m1-M)+ss*__expf(mm-M); m1=M;
    mm=__shfl_xor(m2,off); ss=__shfl_xor(s2,off); M=fmaxf(m2,mm); s2=s2*__expf(m2-M)+ss*__expf(mm-M); m2=M;
    mm=__shfl_xor(m3,off); ss=__shfl_xor(s3,off); M=fmaxf(m3,mm); s3=s3*__expf(m3-M)+ss*__expf(mm-M); m3=M;
  }
  float i0=1.f/(s0+1e-16f), i1=1.f/(s1+1e-16f), i2=1.f/(s2+1e-16f), i3=1.f/(s3+1e-16f);
  int n1 = deg < 64 ? deg : 64;
  if (lane < n1){
    alds[wave][lane][0] = __expf(mylg.x-m0)*i0;
    alds[wave][lane][1] = __expf(mylg.y-m1)*i1;
    alds[wave][lane][2] = __expf(mylg.z-m2)*i2;
    alds[wave][lane][3] = __expf(mylg.w-m3)*i3;
  }
  asm volatile("s_waitcnt lgkmcnt(0)" ::: "memory");
  int head = lane>>4;
  float4 acc0={0,0,0,0}, acc1={0,0,0,0}, acc2={0,0,0,0}, acc3={0,0,0,0};
  int j=0;
  for (; j+4<=n1; j+=4){
    int sn0=ssrc[beg+j], sn1=ssrc[beg+j+1], sn2=ssrc[beg+j+2], sn3=ssrc[beg+j+3];
    float a0=alds[wave][j+0][head], a1=alds[wave][j+1][head];
    float a2=alds[wave][j+2][head], a3=alds[wave][j+3][head];
    ushort4 v0 = ((const ushort4*)(h1bf + (size_t)sn0*F1))[lane];
    ushort4 v1 = ((const ushort4*)(h1bf + (size_t)sn1*F1))[lane];
    ushort4 v2 = ((const ushort4*)(h1bf + (size_t)sn2*F1))[lane];
    ushort4 v3 = ((const ushort4*)(h1bf + (size_t)sn3*F1))[lane];
    acc0.x=fmaf(a0,b2f(v0.x),acc0.x); acc0.y=fmaf(a0,b2f(v0.y),acc0.y); acc0.z=fmaf(a0,b2f(v0.z),acc0.z); acc0.w=fmaf(a0,b2f(v0.w),acc0.w);
    acc1.x=fmaf(a1,b2f(v1.x),acc1.x); acc1.y=fmaf(a1,b2f(v1.y),acc1.y); acc1.z=fmaf(a1,b2f(v1.z),acc1.z); acc1.w=fmaf(a1,b2f(v1.w),acc1.w);
    acc2.x=fmaf(a2,b2f(v2.x),acc2.x); acc2.y=fmaf(a2,b2f(v2.y),acc2.y); acc2.z=fmaf(a2,b2f(v2.z),acc2.z); acc2.w=fmaf(a2,b2f(v2.w),acc2.w);
    acc3.x=fmaf(a3,b2f(v3.x),acc3.x); acc3.y=fmaf(a3,b2f(v3.y),acc3.y); acc3.z=fmaf(a3,b2f(v3.z),acc3.z); acc3.w=fmaf(a3,b2f(v3.w),acc3.w);
  }
  for (; j<n1; j++){
    int sn=ssrc[beg+j];
    float a=alds[wave][j][head];
    ushort4 v = ((const ushort4*)(h1bf + (size_t)sn*F1))[lane];
    acc0.x=fmaf(a,b2f(v.x),acc0.x); acc0.y=fmaf(a,b2f(v.y),acc0.y); acc0.z=fmaf(a,b2f(v.z),acc0.z); acc0.w=fmaf(a,b2f(v.w),acc0.w);
  }
  if (deg > 64){
    float mh = head==0?m0:(head==1?m1:(head==2?m2:m3));
    float ih = head==0?i0:(head==1?i1:(head==2?i2:i3));
    float eh = head==0?edv.x:(head==1?edv.y:(head==2?edv.z:edv.w));
    for (j=64; j<deg; j++){
      int sn=ssrc[beg+j];
      float e = es[(size_t)sn*4+head];
      float a = __expf(leaky(e+eh)-mh)*ih;
      ushort4 v = ((const ushort4*)(h1bf + (size_t)sn*F1))[lane];
      acc0.x=fmaf(a,b2f(v.x),acc0.x); acc0.y=fmaf(a,b2f(v.y),acc0.y); acc0.z=fmaf(a,b2f(v.z),acc0.z); acc0.w=fmaf(a,b2f(v.w),acc0.w);
    }
  }
  float4 acc;
  acc.x = acc0.x+acc1.x+acc2.x+acc3.x;
  acc.y = acc0.y+acc1.y+acc2.y+acc3.y;
  acc.z = acc0.z+acc1.z+acc2.z+acc3.z;
  acc.w = acc0.w+acc1.w+acc2.w+acc3.w;
  float4 bb = *(const float4*)(b1 + lane*4);
  float4 o;
  o.x = elu_f(acc.x + bb.x);
  o.y = elu_f(acc.y + bb.y);
  o.z = elu_f(acc.z + bb.z);
  o.w = elu_f(acc.w + bb.w);
  ushort4 hi, lo;
  hi.x=f2b(o.x); lo.x=f2b(o.x-b2f(hi.x));
  hi.y=f2b(o.y); lo.y=f2b(o.y-b2f(hi.y));
  hi.z=f2b(o.z); lo.z=f2b(o.z-b2f(hi.z));
  hi.w=f2b(o.w); lo.w=f2b(o.w-b2f(hi.w));
  ((ushort4*)(A2hi + (size_t)d*F1))[lane] = hi;
  ((ushort4*)(A2lo + (size_t)d*F1))[lane] = lo;
}

// ---------------- layer-2 aggregation + final mean (bf16 gather) ----------------
__global__ __launch_bounds__(256) void k_agg2(const unsigned short* __restrict__ h2bf, const float* __restrict__ es,
                       const float* __restrict__ ed, const int* __restrict__ offsets,
                       const int* __restrict__ ssrc, const float* __restrict__ b2,
                       float* __restrict__ out){
  __shared__ float alds[4][64];
  int wave=threadIdx.x>>6, lane=threadIdx.x&63;
  int d = blockIdx.x*4+wave; if (d>=N_NODES) return;
  int beg=offsets[d], end=offsets[d+1];
  int deg=end-beg;
  float edv = ed[d];
  float m=-1e30f, s=0.f, mylg=0.f;
  for (int j=lane;j<deg;j+=64){
    float lg = leaky(es[ssrc[beg+j]] + edv);
    if (j==lane) mylg = lg;
    osm(m,s,lg);
  }
  #pragma unroll
  for (int off=1;off<64;off<<=1){
    float m2=__shfl_xor(m,off), ss=__shfl_xor(s,off);
    float M=fmaxf(m,m2); s = s*__expf(m-M)+ss*__expf(m2-M); m=M;
  }
  float inv = 1.f/(s+1e-16f);
  int n1 = deg < 64 ? deg : 64;
  if (lane < n1) alds[wave][lane] = __expf(mylg-m)*inv;
  asm volatile("s_waitcnt lgkmcnt(0)" ::: "memory");
  float2 acc0={0,0}, acc1={0,0}, acc2={0,0}, acc3={0,0};
  int j=0;
  for (; j+4<=n1; j+=4){
    int sn0=ssrc[beg+j], sn1=ssrc[beg+j+1], sn2=ssrc[beg+j+2], sn3=ssrc[beg+j+3];
    float a0=alds[wave][j], a1=alds[wave][j+1], a2=alds[wave][j+2], a3=alds[wave][j+3];
    ushort2 v0 = ((const ushort2*)(h2bf + (size_t)sn0*F2))[lane];
    ushort2 v1 = ((const ushort2*)(h2bf + (size_t)sn1*F2))[lane];
    ushort2 v2 = ((const ushort2*)(h2bf + (size_t)sn2*F2))[lane];
    ushort2 v3 = ((const ushort2*)(h2bf + (size_t)sn3*F2))[lane];
    acc0.x=fmaf(a0,b2f(v0.x),acc0.x); acc0.y=fmaf(a0,b2f(v0.y),acc0.y);
    acc1.x=fmaf(a1,b2f(v1.x),acc1.x); acc1.y=fmaf(a1,b2f(v1.y),acc1.y);
    acc2.x=fmaf(a2,b2f(v2.x),acc2.x); acc2.y=fmaf(a2,b2f(v2.y),acc2.y);
    acc3.x=fmaf(a3,b2f(v3.x),acc3.x); acc3.y=fmaf(a3,b2f(v3.y),acc3.y);
  }
  for (; j<n1; j++){
    int sn=ssrc[beg+j];
    float a=alds[wave][j];
    ushort2 v = ((const ushort2*)(h2bf + (size_t)sn*F2))[lane];
    acc0.x=fmaf(a,b2f(v.x),acc0.x); acc0.y=fmaf(a,b2f(v.y),acc0.y);
  }
  if (deg > 64){
    for (j=64; j<deg; j++){
      int sn=ssrc[beg+j];
      float a = __expf(leaky(es[sn]+edv)-m)*inv;
      ushort2 v = ((const ushort2*)(h2bf + (size_t)sn*F2))[lane];
      acc0.x=fmaf(a,b2f(v.x),acc0.x); acc0.y=fmaf(a,b2f(v.y),acc0.y);
    }
  }
  float2 acc;
  acc.x = acc0.x+acc1.x+acc2.x+acc3.x;
  acc.y = acc0.y+acc1.y+acc2.y+acc3.y;
  float2 bb = *(const float2*)(b2 + lane*2);
  float r = elu_f(acc.x+bb.x) + elu_f(acc.y+bb.y);
  #pragma unroll
  for (int off=1;off<64;off<<=1) r += __shfl_xor(r,off);
  if (lane==0) out[d] = r * (1.f/128.f);
}

extern "C" void kernel_launch(void* const* d_in, const int* in_sizes, int n_in,
                              void* d_out, int out_size, void* d_ws, size_t ws_size,
                              hipStream_t stream) {
  const float* x   = (const float*)d_in[0];
  const int*   ei  = (const int*)d_in[1];
  const int*   esrc = ei;
  const int*   edst = ei + N_EDGES;
  const float* W1  = (const float*)d_in[2];
  const float* a1s = (const float*)d_in[3];
  const float* a1d = (const float*)d_in[4];
  const float* b1  = (const float*)d_in[5];
  const float* W2  = (const float*)d_in[6];
  const float* a2s = (const float*)d_in[7];
  const float* a2d = (const float*)d_in[8];
  const float* b2  = (const float*)d_in[9];
  float* out = (float*)d_out;

  char* ws = (char*)d_ws;
  size_t off = 0;
  auto alloc = [&](size_t bytes)->void*{ void* p = ws + off; off += (bytes + 255) & ~(size_t)255; return p; };
  unsigned short* A1hi = (unsigned short*)alloc((size_t)M_PAD*F1*2);
  unsigned short* A1lo = (unsigned short*)alloc((size_t)M_PAD*F1*2);
  unsigned short* h1bf = (unsigned short*)alloc((size_t)M_PAD*F1*2);
  unsigned short* h2bf = (unsigned short*)alloc((size_t)M_PAD*F2*2);
  unsigned short* Bt1hi= (unsigned short*)alloc((size_t)F1*DIN*2);
  unsigned short* Bt1lo= (unsigned short*)alloc((size_t)F1*DIN*2);
  unsigned short* Bt2hi= (unsigned short*)alloc((size_t)F2*F1*2);
  unsigned short* Bt2lo= (unsigned short*)alloc((size_t)F2*F1*2);
  float* e1s   = (float*)alloc((size_t)N_NODES*HEADS*4);
  float* e1d   = (float*)alloc((size_t)N_NODES*HEADS*4);
  float* e2s   = (float*)alloc((size_t)N_NODES*4);
  float* e2d   = (float*)alloc((size_t)N_NODES*4);
  int*   counts= (int*)alloc((size_t)N_NODES*4);
  int*   offs  = (int*)alloc((size_t)(N_NODES+1)*4);
  int*   cursor= (int*)alloc((size_t)N_NODES*4);
  int*   exc   = (int*)alloc((size_t)N_NODES*4);
  int*   bsum  = (int*)alloc((size_t)SCAN_NBLK*4);
  int*   bpref = (int*)alloc((size_t)SCAN_NBLK*4);
  int*   ssrc  = (int*)alloc((size_t)EP*4);
  unsigned short* A2hi = A1hi;
  unsigned short* A2lo = A1lo;

  hipMemsetAsync(counts, 0, (size_t)N_NODES*4, stream);
  k_hist<<<(EP+255)/256, 256, 0, stream>>>(edst, counts);
  k_scan1<<<SCAN_NBLK, 256, 0, stream>>>(counts, exc, bsum);
  k_scan2<<<1, 256, 0, stream>>>(bsum, bpref, offs);
  k_scan3<<<SCAN_NBLK, 256, 0, stream>>>(exc, bpref, offs, cursor);
  k_scatter<<<(EP+255)/256, 256, 0, stream>>>(esrc, edst, cursor, ssrc);

  k_splitA<<<(M_PAD*F1/4 + 255)/256, 256, 0, stream>>>(x, A1hi, A1lo);
  k_splitWT<<<(DIN*F1 + 255)/256, 256, 0, stream>>>(W1, Bt1hi, Bt1lo, DIN, F1);
  k_splitWT<<<(F1*F2 + 255)/256, 256, 0, stream>>>(W2, Bt2hi, Bt2lo, F1, F2);

  dim3 g1(M_PAD/128, F1/128);
  k_gemm_bf3<<<g1, 256, 0, stream>>>(A1hi, A1lo, Bt1hi, Bt1lo, h1bf, F1);
  k_edot1<<<(N_NODES+3)/4, 256, 0, stream>>>(h1bf, a1s, a1d, e1s, e1d);
  k_agg1<<<(M_PAD+3)/4, 256, 0, stream>>>(h1bf, e1s, e1d, offs, ssrc, b1, A2hi, A2lo);

  dim3 g2(M_PAD/128, F2/128);
  k_gemm_bf3<<<g2, 256, 0, stream>>>(A2hi, A2lo, Bt2hi, Bt2lo, h2bf, F2);
  k_edot2<<<(N_NODES+3)/4, 256, 0, stream>>>(h2bf, a2s, a2d, e2s, e2d);
  k_agg2<<<(N_NODES+3)/4, 256, 0, stream>>>(h2bf, e2s, e2d, offs, ssrc, b2, out);
}